// Round 9
// baseline (239.931 us; speedup 1.0000x reference)
//
#include <hip/hip_runtime.h>

#define DIM 128
#define SLOPE 0.2f
#define NPBK 64            // nodes per bucket (power of 2)
#define SLAB 4000          // slab entries per bucket (mean 2046, +43 sigma)
#define QCAP 1024          // quarter-bucket edge capacity (mean 512, +22 sigma)
#define CHUNK_A 8192       // edges per block in partition kernel
#define EPT 32             // edges per thread (CHUNK_A / 256)
#define KMAX 1024          // max buckets
#define WT_STRIDE 136      // bf16 elems per LDS weight row (16B-aligned, padded)
#define TSTRIDE 136        // tile_hn row stride in ushorts (16B-aligned, bank-safe)

typedef __attribute__((ext_vector_type(8))) short bf16x8;
typedef __attribute__((ext_vector_type(4))) float f32x4;

__device__ __forceinline__ float leaky(float x) { return x > 0.f ? x : SLOPE * x; }

__device__ __forceinline__ unsigned short f2bf(float x) {  // round-to-nearest-even
    unsigned u = __float_as_uint(x);
    return (unsigned short)((u + 0x7FFFu + ((u >> 16) & 1u)) >> 16);
}
__device__ __forceinline__ float bf2f(unsigned short h) {
    return __uint_as_float(((unsigned)h) << 16);
}
__device__ __forceinline__ bf16x8 pack_bf16x8(float4 a, float4 b) {
    bf16x8 r;
    r[0] = (short)f2bf(a.x); r[1] = (short)f2bf(a.y);
    r[2] = (short)f2bf(a.z); r[3] = (short)f2bf(a.w);
    r[4] = (short)f2bf(b.x); r[5] = (short)f2bf(b.y);
    r[6] = (short)f2bf(b.z); r[7] = (short)f2bf(b.w);
    return r;
}

// ---------------------------------------------------------------------------
// K0: v1 = Watt_w @ a1, v2 = Watt_w @ a2, c12; also W2^T -> bf16 global
// ---------------------------------------------------------------------------
__global__ void k_prep(const float* __restrict__ Watt_w, const float* __restrict__ Watt_b,
                       const float* __restrict__ a, const float* __restrict__ W2,
                       float* __restrict__ v1, float* __restrict__ v2,
                       float* __restrict__ c12, unsigned short* __restrict__ Wt_g) {
    int k = threadIdx.x;  // 128 threads
    __shared__ float a1s[DIM], a2s[DIM];
    __shared__ float r1[DIM], r2[DIM];
    a1s[k] = a[k];
    a2s[k] = a[DIM + k];
    __syncthreads();
    float acc1 = 0.f, acc2 = 0.f;
    const float* row = Watt_w + (size_t)k * DIM;
    for (int j = 0; j < DIM; ++j) {
        float w = row[j];
        acc1 += w * a1s[j];
        acc2 += w * a2s[j];
    }
    v1[k] = acc1;
    v2[k] = acc2;
    float b = Watt_b[k];
    r1[k] = b * a1s[k];
    r2[k] = b * a2s[k];
    __syncthreads();
    for (int off = 64; off > 0; off >>= 1) {
        if (k < off) { r1[k] += r1[k + off]; r2[k] += r2[k + off]; }
        __syncthreads();
    }
    if (k == 0) { c12[0] = r1[0]; c12[1] = r2[0]; }
    // W2^T bf16 (Wt_g[n][kk] = W2[kk][n]), row stride DIM
    for (int i = k; i < DIM * DIM; i += 128) {
        int kk = i >> 7, n = i & 127;
        Wt_g[n * DIM + kk] = f2bf(W2[i]);
    }
}

// ---------------------------------------------------------------------------
// K1 (fused heterogeneous): blocks [0, nb_part) partition edges into bucket
// slabs; blocks [nb_part, ...) do the MFMA GEMM h_msg = feat @ W1 + b1
// (+ s1/s2). Independent work, co-scheduled.
// ---------------------------------------------------------------------------
__global__ __launch_bounds__(256) void k_fused_fwd(
    const float* __restrict__ feat, const float* __restrict__ W1,
    const float* __restrict__ W1b, const float* __restrict__ v1,
    const float* __restrict__ v2, const float* __restrict__ c12,
    unsigned short* __restrict__ h_msg, float* __restrict__ s1, float* __restrict__ s2,
    const int* __restrict__ src, const int* __restrict__ dst,
    int* __restrict__ bucket_cur, int* __restrict__ ebuf,
    int n_nodes, int n_tiles16, int n_edges, int K, int nb_part, int total_waves) {
    __shared__ union {
        struct { unsigned short Wt[DIM * WT_STRIDE]; float v1s[DIM]; float v2s[DIM]; } g;
        struct { int h[KMAX]; int lcur[KMAX]; } p;
    } sm;
    int tid = threadIdx.x;

    if (blockIdx.x < nb_part) {
        // ---- partition path ----
        int* h = sm.p.h;
        int* lcur = sm.p.lcur;
        for (int i = tid; i < KMAX; i += 256) h[i] = 0;
        __syncthreads();
        int cbase = blockIdx.x * CHUNK_A;
        int pval[EPT], pb[EPT];
        #pragma unroll
        for (int p = 0; p < 8; ++p) {
            int i0 = cbase + p * 1024 + tid * 4;
            if (i0 + 3 < n_edges) {
                int4 d = *(const int4*)&dst[i0];
                int4 s = *(const int4*)&src[i0];
                int b0 = d.x >> 6, b1 = d.y >> 6, b2 = d.z >> 6, b3 = d.w >> 6;
                atomicAdd(&h[b0], 1); atomicAdd(&h[b1], 1);
                atomicAdd(&h[b2], 1); atomicAdd(&h[b3], 1);
                pb[p * 4 + 0] = b0; pval[p * 4 + 0] = ((d.x & 63) << 17) | s.x;
                pb[p * 4 + 1] = b1; pval[p * 4 + 1] = ((d.y & 63) << 17) | s.y;
                pb[p * 4 + 2] = b2; pval[p * 4 + 2] = ((d.z & 63) << 17) | s.z;
                pb[p * 4 + 3] = b3; pval[p * 4 + 3] = ((d.w & 63) << 17) | s.w;
            } else {
                #pragma unroll
                for (int k = 0; k < 4; ++k) {
                    int i = i0 + k;
                    if (i < n_edges) {
                        int d = dst[i], s = src[i];
                        int b = d >> 6;
                        atomicAdd(&h[b], 1);
                        pb[p * 4 + k] = b;
                        pval[p * 4 + k] = ((d & 63) << 17) | s;
                    } else {
                        pb[p * 4 + k] = -1;
                        pval[p * 4 + k] = 0;
                    }
                }
            }
        }
        __syncthreads();
        for (int i = tid; i < K; i += 256) {
            int c = h[i];
            lcur[i] = c ? (i * SLAB + atomicAdd(&bucket_cur[i], c)) : 0;
        }
        __syncthreads();
        #pragma unroll
        for (int k = 0; k < EPT; ++k) {
            int b = pb[k];
            if (b >= 0) {
                int pos = atomicAdd(&lcur[b], 1);
                ebuf[pos] = pval[k];
            }
        }
        return;
    }

    // ---- node-forward MFMA path ----
    unsigned short* Wt = sm.g.Wt;
    float* v1s = sm.g.v1s;
    float* v2s = sm.g.v2s;
    for (int i = tid; i < DIM * DIM; i += 256) {
        int k = i >> 7, n = i & 127;        // W1[k][n] row-major
        Wt[n * WT_STRIDE + k] = f2bf(W1[i]);
    }
    if (tid < DIM) { v1s[tid] = v1[tid]; v2s[tid] = v2[tid]; }
    __syncthreads();

    int lane = tid & 63, wid = tid >> 6;
    int ln15 = lane & 15, q = lane >> 4;
    float c1 = c12[0], c2 = c12[1];
    float bias[8];
    #pragma unroll
    for (int nt = 0; nt < 8; ++nt) bias[nt] = W1b[nt * 16 + ln15];

    for (int t = (blockIdx.x - nb_part) * 4 + wid; t < n_tiles16; t += total_waves) {
        int base = t * 16;
        int row = base + ln15;
        bool valid = row < n_nodes;
        const float* frow = feat + (size_t)row * DIM;
        bf16x8 afr[4];
        float p1 = 0.f, p2 = 0.f;
        #pragma unroll
        for (int kc = 0; kc < 4; ++kc) {
            int col0 = kc * 32 + q * 8;
            float4 u0 = {0.f, 0.f, 0.f, 0.f}, u1 = {0.f, 0.f, 0.f, 0.f};
            if (valid) {
                u0 = *(const float4*)&frow[col0];
                u1 = *(const float4*)&frow[col0 + 4];
            }
            float4 wa = *(const float4*)&v1s[col0];
            float4 wb = *(const float4*)&v1s[col0 + 4];
            float4 wc = *(const float4*)&v2s[col0];
            float4 wd = *(const float4*)&v2s[col0 + 4];
            p1 += u0.x * wa.x + u0.y * wa.y + u0.z * wa.z + u0.w * wa.w
                + u1.x * wb.x + u1.y * wb.y + u1.z * wb.z + u1.w * wb.w;
            p2 += u0.x * wc.x + u0.y * wc.y + u0.z * wc.z + u0.w * wc.w
                + u1.x * wd.x + u1.y * wd.y + u1.z * wd.z + u1.w * wd.w;
            afr[kc] = pack_bf16x8(u0, u1);
        }
        p1 += __shfl_xor(p1, 16, 64); p1 += __shfl_xor(p1, 32, 64);
        p2 += __shfl_xor(p2, 16, 64); p2 += __shfl_xor(p2, 32, 64);
        if (q == 0 && valid) { s1[row] = p1 + c1; s2[row] = p2 + c2; }

        f32x4 acc[8];
        #pragma unroll
        for (int nt = 0; nt < 8; ++nt)
            acc[nt] = (f32x4){bias[nt], bias[nt], bias[nt], bias[nt]};
        #pragma unroll
        for (int kc = 0; kc < 4; ++kc) {
            #pragma unroll
            for (int nt = 0; nt < 8; ++nt) {
                bf16x8 b = *(const bf16x8*)&Wt[(nt * 16 + ln15) * WT_STRIDE + kc * 32 + q * 8];
                acc[nt] = __builtin_amdgcn_mfma_f32_16x16x32_bf16(afr[kc], b, acc[nt], 0, 0, 0);
            }
        }
        #pragma unroll
        for (int nt = 0; nt < 8; ++nt) {
            #pragma unroll
            for (int r = 0; r < 4; ++r) {
                int rr = base + q * 4 + r;
                if (rr < n_nodes)
                    h_msg[(size_t)rr * DIM + nt * 16 + ln15] = f2bf(acc[nt][r]);
            }
        }
    }
}

// ---------------------------------------------------------------------------
// K2 (quarter-bucket back half): one 256-thr block per 16 dst nodes.
//   phase 1: filter this quarter's edges from the bucket slab; LDS counting
//            sort; exp computed ONCE per edge, packed src|bf16(e) in LDS.
//   phase 2: gather (8 groups of 32 lanes, work-stealing over 16 nodes) ->
//            normalized h_neigh tile (bf16) in LDS (stride 136: bank-safe).
//   phase 3: W2 MFMA (4 waves x 2 nt-tiles), B-frags from global bf16 W2^T,
//            epilogue with exact residual -> out.
// ---------------------------------------------------------------------------
__global__ __launch_bounds__(256, 6) void k_back(
    const int* __restrict__ ebuf, const int* __restrict__ bucket_cur,
    const float* __restrict__ s1, const float* __restrict__ s2,
    const unsigned short* __restrict__ h_msg, const float* __restrict__ feat,
    const unsigned short* __restrict__ Wt_g, const float* __restrict__ W2b,
    float* __restrict__ out, int n_nodes) {
    __shared__ int psorted[QCAP];                    // src | bf16(exp)<<16
    __shared__ unsigned short tile_hn[16 * TSTRIDE]; // bf16 h_neigh tile
    __shared__ float s2loc[16];
    __shared__ int bins16[16], scn16[16], cur16[16];
    __shared__ int next_node;

    int tid = threadIdx.x;
    int b = blockIdx.x >> 2;          // bucket
    int qid = blockIdx.x & 3;         // quarter within bucket
    int base16 = b * NPBK + qid * 16; // first dst node of this block
    int start = b * SLAB;
    int cnt = bucket_cur[b];

    if (tid < 16) {
        bins16[tid] = 0;
        int g = base16 + tid;
        s2loc[tid] = (g < n_nodes) ? s2[g] : 0.f;
    }
    if (tid == 0) next_node = 0;
    __syncthreads();

    // phase 1a: count this quarter's edges per local node
    for (int i = tid; i < cnt; i += 256) {
        int v = ebuf[start + i];
        int dl = v >> 17;
        if ((dl >> 4) == qid) atomicAdd(&bins16[dl & 15], 1);
    }
    __syncthreads();
    if (tid == 0) {
        int run = 0;
        for (int k = 0; k < 16; ++k) { scn16[k] = run; cur16[k] = run; run += bins16[k]; }
    }
    __syncthreads();
    // phase 1b: place + one exp per edge
    for (int i = tid; i < cnt; i += 256) {
        int v = ebuf[start + i];
        int dl = v >> 17;
        if ((dl >> 4) == qid) {
            int s = v & 0x1FFFF;
            int p = atomicAdd(&cur16[dl & 15], 1);
            float e = __expf(leaky(s1[s] + s2loc[dl & 15]));
            psorted[p] = s | (((int)f2bf(e)) << 16);
        }
    }
    __syncthreads();

    // phase 2: gather, 32-lane groups work-stealing over 16 nodes
    int lane = tid & 31;
    while (true) {
        int gl;
        if (lane == 0) gl = atomicAdd(&next_node, 1);
        gl = __shfl(gl, 0, 32);
        if (gl >= 16) break;
        int g = base16 + gl;
        if (g >= n_nodes) {
            *(ushort4*)&tile_hn[gl * TSTRIDE + lane * 4] = (ushort4){0, 0, 0, 0};
            continue;
        }
        int begin = scn16[gl];
        int end = begin + bins16[gl];
        float4 accA = {0.f, 0.f, 0.f, 0.f}, accB = {0.f, 0.f, 0.f, 0.f};
        float wA = 0.f, wB = 0.f;
        int j = begin;
        int vA = (j < end) ? psorted[j] : 0;
        int vB = (j + 1 < end) ? psorted[j + 1] : 0;
        while (j + 1 < end) {
            int cA = vA & 0xFFFF, cB = vB & 0xFFFF;
            float eA = bf2f((unsigned short)(((unsigned)vA) >> 16));
            float eB = bf2f((unsigned short)(((unsigned)vB) >> 16));
            int jn = j + 2;
            if (jn < end)     vA = psorted[jn];
            if (jn + 1 < end) vB = psorted[jn + 1];
            ushort4 uA = *(const ushort4*)&h_msg[(size_t)cA * DIM + lane * 4];
            ushort4 uB = *(const ushort4*)&h_msg[(size_t)cB * DIM + lane * 4];
            accA.x += eA * bf2f(uA.x); accA.y += eA * bf2f(uA.y);
            accA.z += eA * bf2f(uA.z); accA.w += eA * bf2f(uA.w);
            wA += eA;
            accB.x += eB * bf2f(uB.x); accB.y += eB * bf2f(uB.y);
            accB.z += eB * bf2f(uB.z); accB.w += eB * bf2f(uB.w);
            wB += eB;
            j = jn;
        }
        if (j < end) {
            int cA = vA & 0xFFFF;
            float eA = bf2f((unsigned short)(((unsigned)vA) >> 16));
            ushort4 uA = *(const ushort4*)&h_msg[(size_t)cA * DIM + lane * 4];
            accA.x += eA * bf2f(uA.x); accA.y += eA * bf2f(uA.y);
            accA.z += eA * bf2f(uA.z); accA.w += eA * bf2f(uA.w);
            wA += eA;
        }
        float inv = 1.f / (wA + wB + 1e-9f);
        ushort4 o;
        o.x = f2bf((accA.x + accB.x) * inv);
        o.y = f2bf((accA.y + accB.y) * inv);
        o.z = f2bf((accA.z + accB.z) * inv);
        o.w = f2bf((accA.w + accB.w) * inv);
        *(ushort4*)&tile_hn[gl * TSTRIDE + lane * 4] = o;
    }
    __syncthreads();

    // phase 3: W2 MFMA. wave w (0..3): nt-pair = w*2; A = bf16(f * hn)
    int w = tid >> 6;
    int lane64 = tid & 63;
    int ln15 = lane64 & 15, q = lane64 >> 4;
    int nt0 = w * 2;
    int grow = base16 + ln15;
    bool valid = grow < n_nodes;
    const float* frow = feat + (size_t)grow * DIM;
    bf16x8 afr[4];
    #pragma unroll
    for (int kc = 0; kc < 4; ++kc) {
        int col0 = kc * 32 + q * 8;
        float4 p0 = {0.f, 0.f, 0.f, 0.f}, p1 = {0.f, 0.f, 0.f, 0.f};
        bf16x8 hn8 = *(const bf16x8*)&tile_hn[ln15 * TSTRIDE + col0];
        if (valid) {
            float4 f0 = *(const float4*)&frow[col0];
            float4 f1 = *(const float4*)&frow[col0 + 4];
            p0.x = f0.x * bf2f((unsigned short)hn8[0]);
            p0.y = f0.y * bf2f((unsigned short)hn8[1]);
            p0.z = f0.z * bf2f((unsigned short)hn8[2]);
            p0.w = f0.w * bf2f((unsigned short)hn8[3]);
            p1.x = f1.x * bf2f((unsigned short)hn8[4]);
            p1.y = f1.y * bf2f((unsigned short)hn8[5]);
            p1.z = f1.z * bf2f((unsigned short)hn8[6]);
            p1.w = f1.w * bf2f((unsigned short)hn8[7]);
        }
        afr[kc] = pack_bf16x8(p0, p1);
    }
    f32x4 acc0, acc1;
    {
        float b0 = W2b[(nt0 + 0) * 16 + ln15];
        float b1 = W2b[(nt0 + 1) * 16 + ln15];
        acc0 = (f32x4){b0, b0, b0, b0};
        acc1 = (f32x4){b1, b1, b1, b1};
    }
    #pragma unroll
    for (int kc = 0; kc < 4; ++kc) {
        bf16x8 w0 = *(const bf16x8*)&Wt_g[((nt0 + 0) * 16 + ln15) * DIM + kc * 32 + q * 8];
        bf16x8 w1 = *(const bf16x8*)&Wt_g[((nt0 + 1) * 16 + ln15) * DIM + kc * 32 + q * 8];
        acc0 = __builtin_amdgcn_mfma_f32_16x16x32_bf16(afr[kc], w0, acc0, 0, 0, 0);
        acc1 = __builtin_amdgcn_mfma_f32_16x16x32_bf16(afr[kc], w1, acc1, 0, 0, 0);
    }
    #pragma unroll
    for (int r = 0; r < 4; ++r) {
        int rl = q * 4 + r;
        int rr = base16 + rl;
        if (rr < n_nodes) {
            int colA = (nt0 + 0) * 16 + ln15;
            int colB = (nt0 + 1) * 16 + ln15;
            float fA = feat[(size_t)rr * DIM + colA];
            float fB = feat[(size_t)rr * DIM + colB];
            float hA = bf2f(tile_hn[rl * TSTRIDE + colA]);
            float hB = bf2f(tile_hn[rl * TSTRIDE + colB]);
            out[(size_t)rr * DIM + colA] = leaky(fA + hA + acc0[r]);
            out[(size_t)rr * DIM + colB] = leaky(fB + hB + acc1[r]);
        }
    }
}

// ---------------------------------------------------------------------------
extern "C" void kernel_launch(void* const* d_in, const int* in_sizes, int n_in,
                              void* d_out, int out_size, void* d_ws, size_t ws_size,
                              hipStream_t stream) {
    const int*   indices = (const int*)d_in[0];
    const float* feat    = (const float*)d_in[1];
    const float* W1w  = (const float*)d_in[3];
    const float* W1b  = (const float*)d_in[4];
    const float* W2w  = (const float*)d_in[5];
    const float* W2b  = (const float*)d_in[6];
    const float* Wattw = (const float*)d_in[7];
    const float* Wattb = (const float*)d_in[8];
    const float* a     = (const float*)d_in[9];

    int n_edges = in_sizes[0] / 2;
    int n_nodes = in_sizes[1] / DIM;
    int n_tiles16 = (n_nodes + 15) / 16;
    int K = (n_nodes + NPBK - 1) / NPBK;       // 782 buckets for 50k nodes
    const int* src = indices;
    const int* dst = indices + n_edges;

    float* ws      = (float*)d_ws;
    unsigned short* h_msg = (unsigned short*)ws;              // n*DIM bf16 (12.8 MB)
    int*   ebuf    = (int*)(h_msg + (size_t)n_nodes * DIM);   // K*SLAB i (12.5 MB)
    float* s1      = (float*)(ebuf + (size_t)K * SLAB);       // n f
    float* s2      = s1 + n_nodes;                            // n f
    float* v1      = s2 + n_nodes;                            // DIM f
    float* v2      = v1 + DIM;                                // DIM f
    float* c12     = v2 + DIM;                                // 2 f
    int*   bucket_cur = (int*)(c12 + 2);                      // KMAX i
    unsigned short* Wt_g = (unsigned short*)(bucket_cur + KMAX); // DIM*DIM bf16 (32 KB)

    hipMemsetAsync(bucket_cur, 0, (size_t)KMAX * sizeof(int), stream);

    k_prep<<<1, 128, 0, stream>>>(Wattw, Wattb, a, W2w, v1, v2, c12, Wt_g);
    {
        int nb_part = (n_edges + CHUNK_A - 1) / CHUNK_A;   // 196
        int gemm_blocks = 512;
        k_fused_fwd<<<nb_part + gemm_blocks, 256, 0, stream>>>(
            feat, W1w, W1b, v1, v2, c12, h_msg, s1, s2,
            src, dst, bucket_cur, ebuf,
            n_nodes, n_tiles16, n_edges, K, nb_part, gemm_blocks * 4);
    }
    k_back<<<K * 4, 256, 0, stream>>>(ebuf, bucket_cur, s1, s2, h_msg, feat,
                                      Wt_g, W2b, (float*)d_out, n_nodes);
}